// Round 14
// baseline (69.773 us; speedup 1.0000x reference)
//
#include <hip/hip_runtime.h>

#define NBINS 128
#define NFREQ 64
#define HDIM 128
#define NQ 16384
#define EPSF 1e-8f

typedef _Float16 h2 __attribute__((ext_vector_type(2)));
typedef _Float16 f16x4 __attribute__((ext_vector_type(4)));
typedef float f32x4 __attribute__((ext_vector_type(4)));
#define U32(x) __builtin_bit_cast(unsigned, (x))

// ---- d_ws layout (dword offsets) ----
// Bw : [btile(8)][f(64)] records of 17 b64 slots (slot b&15; slot16 = 0)
//      slot = { h2(pr,pi), h2(pm2+eps, 1) }                     17408 dw
// W  : [f(64)][b(128)] f32 (-softplus(w))                        8192 dw
// mwB: [btile(8)][kc(4)][lane(64)] b64 of 4 f16 mw               4096 dw
// qmA: [qtile(1024)][kc(4)][lane(64)] b64 of 4 f16 qmag        524288 dw
// Aw : [qtile(1024)][f(64)] records of 17 b64 slots (slot q&15; slot16 = 0)
//      slot = { h2(-2qr,-2qi), h2(1, qm2) }                   2228224 dw
#define BW_O 0
#define W_O 17408
#define MWB_O 25600
#define QMA_O 29696
#define AW_O 553984
#define WS_END_DW (AW_O + 1024 * 64 * 34)

#define QN_BLOCKS 256   // q-side prologue blocks
#define PB_BLOCKS 2     // probe-side prologue blocks

__global__ __launch_bounds__(256) void prologue14(
    const float* __restrict__ Q,
    const float* __restrict__ probes,
    const float* __restrict__ wraw,
    const float* __restrict__ mw,
    unsigned* __restrict__ ws) {
  const int blk = blockIdx.x;
  const int t = threadIdx.x;
  char* wsb = (char*)ws;
  if (blk < QN_BLOCKS) {
    // ---- q side: 4 lanes per query; lane l2 owns freqs [16*l2, 16*l2+16) ----
    const int l2 = t & 3;
    const int q = blk * 64 + (t >> 2);
    const float* qp = Q + (size_t)q * HDIM;
    float re[16], im[16];
    #pragma unroll
    for (int k = 0; k < 4; ++k) {
      *reinterpret_cast<float4*>(&re[k * 4]) =
          *reinterpret_cast<const float4*>(qp + 16 * l2 + k * 4);
      *reinterpret_cast<float4*>(&im[k * 4]) =
          *reinterpret_cast<const float4*>(qp + NFREQ + 16 * l2 + k * 4);
    }
    float s = 0.0f;
    #pragma unroll
    for (int k = 0; k < 16; ++k) {
      s = fmaf(re[k], re[k], s);
      s = fmaf(im[k], im[k], s);
    }
    s += __shfl_xor(s, 1, 4);
    s += __shfl_xor(s, 2, 4);
    const float inv = 1.0f / (__builtin_amdgcn_sqrtf(s) + EPSF);
    const int qtile = q >> 4, qs = q & 15;
    float qmv[16];
    #pragma unroll
    for (int k = 0; k < 16; ++k) {
      const int f = 16 * l2 + k;
      const float qr = re[k] * inv;
      const float qi = im[k] * inv;
      const float qm2 = fmaf(qr, qr, qi * qi);
      qmv[k] = __builtin_amdgcn_sqrtf(qm2 + EPSF);
      h2 w0 = {(_Float16)(-2.0f * qr), (_Float16)(-2.0f * qi)};
      h2 w1 = {(_Float16)1.0f, (_Float16)qm2};
      char* rec = wsb + (size_t)AW_O * 4 + ((size_t)qtile * 64 + f) * 136;
      *reinterpret_cast<uint2*>(rec + qs * 8) = make_uint2(U32(w0), U32(w1));
      if (qs == 0) *reinterpret_cast<uint2*>(rec + 128) = make_uint2(0u, 0u);
    }
    // qmA: kc = l2; lane-index = qs + 16*fg; 4 f16 per b64 (j = k&3)
    #pragma unroll
    for (int fg = 0; fg < 4; ++fg) {
      f16x4 v = {(_Float16)qmv[fg * 4], (_Float16)qmv[fg * 4 + 1],
                 (_Float16)qmv[fg * 4 + 2], (_Float16)qmv[fg * 4 + 3]};
      char* p = wsb + (size_t)QMA_O * 4 + ((size_t)qtile * 4 + l2) * 512 +
                (qs + 16 * fg) * 8;
      *reinterpret_cast<f16x4*>(p) = v;
    }
  } else {
    // ---- probe side: 512 ids; id -> (b, 16-freq group) ----
    const int id = (blk - QN_BLOCKS) * 256 + t;
    if (id >= 512) return;
    const int b = id >> 2, l2 = id & 3;
    const int btile = b >> 4, bs = b & 15;
    float mvals[16];
    #pragma unroll
    for (int k = 0; k < 16; ++k) {
      const int f = 16 * l2 + k;
      const float pr = probes[b * HDIM + f];
      const float pi = probes[b * HDIM + NFREQ + f];
      const float x = wraw[b * NFREQ + f];
      const float wv = -(fmaxf(x, 0.0f) + log1pf(expf(-fabsf(x))));  // -softplus
      mvals[k] = mw[b * NFREQ + f];
      const float pm2e = fmaf(pr, pr, fmaf(pi, pi, EPSF));
      h2 w0 = {(_Float16)pr, (_Float16)pi};
      h2 w1 = {(_Float16)pm2e, (_Float16)1.0f};
      char* rec = wsb + (size_t)BW_O * 4 + ((size_t)btile * 64 + f) * 136;
      *reinterpret_cast<uint2*>(rec + bs * 8) = make_uint2(U32(w0), U32(w1));
      if (bs == 0) *reinterpret_cast<uint2*>(rec + 128) = make_uint2(0u, 0u);
      *reinterpret_cast<float*>(wsb + (size_t)W_O * 4 + f * 512 + b * 4) = wv;
    }
    #pragma unroll
    for (int fg = 0; fg < 4; ++fg) {
      f16x4 v = {(_Float16)mvals[fg * 4], (_Float16)mvals[fg * 4 + 1],
                 (_Float16)mvals[fg * 4 + 2], (_Float16)mvals[fg * 4 + 3]};
      char* p = wsb + (size_t)MWB_O * 4 + ((size_t)btile * 4 + l2) * 512 +
                (bs + 16 * fg) * 8;
      *reinterpret_cast<f16x4*>(p) = v;
    }
  }
}

// ---- scorer14: per-freq d^2 via MFMA; sqrt+weight on VALU; mag via dense MFMA ----
// Block 256 thr = 4 waves. blockIdx: qtile = bid>>1, bh = bid&1; wave -> btile = bh*4+wv.
// Wave computes the full 16q x 16b output tile over all 64 freqs.
__global__ __launch_bounds__(256) void scorer14(
    const unsigned* __restrict__ ws,
    const float* __restrict__ bias,
    float* __restrict__ out) {
  const int t = threadIdx.x;
  const int l = t & 63;
  const int wv = __builtin_amdgcn_readfirstlane(t >> 6);
  const int qtile = blockIdx.x >> 1;
  const int btile = (blockIdx.x & 1) * 4 + wv;
  const int l15 = l & 15;
  const int lrow = l >> 4;
  const int lmin = l < 16 ? l : 16;     // lanes >=16 hit the zero slot
  const char* wsb = (const char*)ws;

  const char* Abase = wsb + (size_t)AW_O * 4 + (size_t)qtile * 64 * 136 + lmin * 8;
  const char* Bbase = wsb + (size_t)BW_O * 4 + (size_t)btile * 64 * 136 + lmin * 8;
  const char* Wbase = wsb + (size_t)W_O * 4 + btile * 64 + l15 * 4;

  f32x4 dacc = {0.0f, 0.0f, 0.0f, 0.0f};
  f32x4 macc = {0.0f, 0.0f, 0.0f, 0.0f};

  // magnitude term: 4 dense K=16 mfmas chained into macc
  #pragma unroll
  for (int kc = 0; kc < 4; ++kc) {
    f16x4 aM = *reinterpret_cast<const f16x4*>(
        wsb + (size_t)QMA_O * 4 + ((size_t)qtile * 4 + kc) * 512 + l * 8);
    f16x4 bM = *reinterpret_cast<const f16x4*>(
        wsb + (size_t)MWB_O * 4 + ((size_t)btile * 4 + kc) * 512 + l * 8);
    macc = __builtin_amdgcn_mfma_f32_16x16x16f16(aM, bM, macc, 0, 0, 0);
  }

  // distance term: one mfma per freq -> d^2 tile; sqrt + weighted accumulate
  #pragma unroll 8
  for (int f = 0; f < NFREQ; ++f) {
    const f16x4 aF = *reinterpret_cast<const f16x4*>(Abase + f * 136);
    const f16x4 bF = *reinterpret_cast<const f16x4*>(Bbase + f * 136);
    const f32x4 zero = {0.0f, 0.0f, 0.0f, 0.0f};
    f32x4 d2 = __builtin_amdgcn_mfma_f32_16x16x16f16(aF, bF, zero, 0, 0, 0);
    const float w = *reinterpret_cast<const float*>(Wbase + f * 512);
    #pragma unroll
    for (int r = 0; r < 4; ++r) {
      const float d = __builtin_amdgcn_sqrtf(fmaxf(d2[r], EPSF));
      dacc[r] = fmaf(d, w, dacc[r]);
    }
  }

  // epilogue: out[q, b] = dacc + macc + bias[b]
  const float bv = bias[btile * 16 + l15];
  #pragma unroll
  for (int r = 0; r < 4; ++r) {
    const int q = qtile * 16 + lrow * 4 + r;
    out[(size_t)q * NBINS + btile * 16 + l15] = dacc[r] + macc[r] + bv;
  }
}

extern "C" void kernel_launch(void* const* d_in, const int* in_sizes, int n_in,
                              void* d_out, int out_size, void* d_ws, size_t ws_size,
                              hipStream_t stream) {
  const float* Q      = (const float*)d_in[0];
  const float* probes = (const float*)d_in[1];
  const float* wraw   = (const float*)d_in[2];
  const float* mw     = (const float*)d_in[3];
  const float* bias   = (const float*)d_in[4];
  float* out = (float*)d_out;
  unsigned* ws = (unsigned*)d_ws;  // needs ~11.2 MB; harness provides 256 MB

  prologue14<<<QN_BLOCKS + PB_BLOCKS, 256, 0, stream>>>(Q, probes, wraw, mw, ws);
  scorer14<<<2048, 256, 0, stream>>>(ws, bias, out);
}

// Round 15
// 69.389 us; speedup vs baseline: 1.0055x; 1.0055x over previous
//
#include <hip/hip_runtime.h>

#define NBINS 128
#define NFREQ 64
#define HDIM 128
#define NQ 16384
#define EPSF 1e-8f

typedef _Float16 h2 __attribute__((ext_vector_type(2)));
typedef _Float16 f16x4 __attribute__((ext_vector_type(4)));
typedef float f32x4 __attribute__((ext_vector_type(4)));
#define U32(x) __builtin_bit_cast(unsigned, (x))

// ---- d_ws layout (dword offsets) ----
// Bw : [btile(8)][f(64)] records of 17 b64 slots (slot b&15; slot16 = 0)
//      slot = { h2(pr,pi), h2(pm2+eps, 1) }                     17408 dw
// W  : [b(128)][f(64)] f32 (-softplus(w))  (ROW-MAJOR per bin)   8192 dw
// mwB: [btile(8)][kc(4)][lane(64)] b64 of 4 f16 mw               4096 dw
// qmA: [qtile(1024)][kc(4)][lane(64)] b64 of 4 f16 qmag        524288 dw
// Aw : [qtile(1024)][f(64)] records of 17 b64 slots (slot q&15; slot16 = 0)
//      slot = { h2(-2qr,-2qi), h2(1, qm2) }
#define BW_O 0
#define W_O 17408
#define MWB_O 25600
#define QMA_O 29696
#define AW_O 553984

#define QN_BLOCKS 256   // q-side prologue blocks
#define PB_BLOCKS 2     // probe-side prologue blocks

__global__ __launch_bounds__(256) void prologue15(
    const float* __restrict__ Q,
    const float* __restrict__ probes,
    const float* __restrict__ wraw,
    const float* __restrict__ mw,
    unsigned* __restrict__ ws) {
  const int blk = blockIdx.x;
  const int t = threadIdx.x;
  char* wsb = (char*)ws;
  if (blk < QN_BLOCKS) {
    // ---- q side: 4 lanes per query; lane l2 owns freqs [16*l2, 16*l2+16) ----
    const int l2 = t & 3;
    const int q = blk * 64 + (t >> 2);
    const float* qp = Q + (size_t)q * HDIM;
    float re[16], im[16];
    #pragma unroll
    for (int k = 0; k < 4; ++k) {
      *reinterpret_cast<float4*>(&re[k * 4]) =
          *reinterpret_cast<const float4*>(qp + 16 * l2 + k * 4);
      *reinterpret_cast<float4*>(&im[k * 4]) =
          *reinterpret_cast<const float4*>(qp + NFREQ + 16 * l2 + k * 4);
    }
    float s = 0.0f;
    #pragma unroll
    for (int k = 0; k < 16; ++k) {
      s = fmaf(re[k], re[k], s);
      s = fmaf(im[k], im[k], s);
    }
    s += __shfl_xor(s, 1, 4);
    s += __shfl_xor(s, 2, 4);
    const float inv = 1.0f / (__builtin_amdgcn_sqrtf(s) + EPSF);
    const int qtile = q >> 4, qs = q & 15;
    float qmv[16];
    #pragma unroll
    for (int k = 0; k < 16; ++k) {
      const int f = 16 * l2 + k;
      const float qr = re[k] * inv;
      const float qi = im[k] * inv;
      const float qm2 = fmaf(qr, qr, qi * qi);
      qmv[k] = __builtin_amdgcn_sqrtf(qm2 + EPSF);
      h2 w0 = {(_Float16)(-2.0f * qr), (_Float16)(-2.0f * qi)};
      h2 w1 = {(_Float16)1.0f, (_Float16)qm2};
      char* rec = wsb + (size_t)AW_O * 4 + ((size_t)qtile * 64 + f) * 136;
      *reinterpret_cast<uint2*>(rec + qs * 8) = make_uint2(U32(w0), U32(w1));
      if (qs == 0) *reinterpret_cast<uint2*>(rec + 128) = make_uint2(0u, 0u);
    }
    #pragma unroll
    for (int fg = 0; fg < 4; ++fg) {
      f16x4 v = {(_Float16)qmv[fg * 4], (_Float16)qmv[fg * 4 + 1],
                 (_Float16)qmv[fg * 4 + 2], (_Float16)qmv[fg * 4 + 3]};
      char* p = wsb + (size_t)QMA_O * 4 + ((size_t)qtile * 4 + l2) * 512 +
                (qs + 16 * fg) * 8;
      *reinterpret_cast<f16x4*>(p) = v;
    }
  } else {
    // ---- probe side: 512 ids; id -> (b, 16-freq group) ----
    const int id = (blk - QN_BLOCKS) * 256 + t;
    if (id >= 512) return;
    const int b = id >> 2, l2 = id & 3;
    const int btile = b >> 4, bs = b & 15;
    float mvals[16];
    #pragma unroll
    for (int k = 0; k < 16; ++k) {
      const int f = 16 * l2 + k;
      const float pr = probes[b * HDIM + f];
      const float pi = probes[b * HDIM + NFREQ + f];
      const float x = wraw[b * NFREQ + f];
      const float wv = -(fmaxf(x, 0.0f) + log1pf(expf(-fabsf(x))));  // -softplus
      mvals[k] = mw[b * NFREQ + f];
      const float pm2e = fmaf(pr, pr, fmaf(pi, pi, EPSF));
      h2 w0 = {(_Float16)pr, (_Float16)pi};
      h2 w1 = {(_Float16)pm2e, (_Float16)1.0f};
      char* rec = wsb + (size_t)BW_O * 4 + ((size_t)btile * 64 + f) * 136;
      *reinterpret_cast<uint2*>(rec + bs * 8) = make_uint2(U32(w0), U32(w1));
      if (bs == 0) *reinterpret_cast<uint2*>(rec + 128) = make_uint2(0u, 0u);
      // W row-major per bin: lane-local 256B row in the scorer
      *reinterpret_cast<float*>(wsb + (size_t)W_O * 4 + ((size_t)b * 64 + f) * 4) = wv;
    }
    #pragma unroll
    for (int fg = 0; fg < 4; ++fg) {
      f16x4 v = {(_Float16)mvals[fg * 4], (_Float16)mvals[fg * 4 + 1],
                 (_Float16)mvals[fg * 4 + 2], (_Float16)mvals[fg * 4 + 3]};
      char* p = wsb + (size_t)MWB_O * 4 + ((size_t)btile * 4 + l2) * 512 +
                (bs + 16 * fg) * 8;
      *reinterpret_cast<f16x4*>(p) = v;
    }
  }
}

// ---- scorer15: r14's MFMA algorithm with batch-preload ILP ----
// Wave = full 16q x 16b tile over 64 freqs. 4 chunks of 16 freqs:
// preload aF[16], bF[16], w[16] -> 16 independent mfmas -> sqrt/fma epilogues.
__global__ __launch_bounds__(256) void scorer15(
    const unsigned* __restrict__ ws,
    const float* __restrict__ bias,
    float* __restrict__ out) {
  const int t = threadIdx.x;
  const int l = t & 63;
  const int wv = __builtin_amdgcn_readfirstlane(t >> 6);
  const int qtile = blockIdx.x >> 1;
  const int btile = (blockIdx.x & 1) * 4 + wv;
  const int l15 = l & 15;
  const int lrow = l >> 4;
  const int lmin = l < 16 ? l : 16;     // lanes >=16 hit the zero slot
  const char* wsb = (const char*)ws;

  const char* Abase = wsb + (size_t)AW_O * 4 + (size_t)qtile * 64 * 136 + lmin * 8;
  const char* Bbase = wsb + (size_t)BW_O * 4 + (size_t)btile * 64 * 136 + lmin * 8;
  const float* Wrow = reinterpret_cast<const float*>(wsb + (size_t)W_O * 4) +
                      (size_t)(btile * 16 + l15) * 64;

  f32x4 dacc = {0.0f, 0.0f, 0.0f, 0.0f};
  f32x4 macc = {0.0f, 0.0f, 0.0f, 0.0f};

  // magnitude term: 4 dense K=16 mfmas chained into macc
  #pragma unroll
  for (int kc = 0; kc < 4; ++kc) {
    f16x4 aM = *reinterpret_cast<const f16x4*>(
        wsb + (size_t)QMA_O * 4 + ((size_t)qtile * 4 + kc) * 512 + l * 8);
    f16x4 bM = *reinterpret_cast<const f16x4*>(
        wsb + (size_t)MWB_O * 4 + ((size_t)btile * 4 + kc) * 512 + l * 8);
    macc = __builtin_amdgcn_mfma_f32_16x16x16f16(aM, bM, macc, 0, 0, 0);
  }

  // distance term: 4 chunks x 16 freqs, batch-preloaded for ILP
  #pragma unroll 1
  for (int c = 0; c < 4; ++c) {
    f16x4 aF[16], bF[16];
    float w16[16];
    #pragma unroll
    for (int k = 0; k < 16; ++k) {
      aF[k] = *reinterpret_cast<const f16x4*>(Abase + (size_t)(c * 16 + k) * 136);
      bF[k] = *reinterpret_cast<const f16x4*>(Bbase + (size_t)(c * 16 + k) * 136);
    }
    #pragma unroll
    for (int g = 0; g < 4; ++g)
      *reinterpret_cast<float4*>(&w16[g * 4]) =
          *reinterpret_cast<const float4*>(Wrow + c * 16 + g * 4);
    #pragma unroll
    for (int k = 0; k < 16; ++k) {
      const f32x4 zero = {0.0f, 0.0f, 0.0f, 0.0f};
      f32x4 d2 = __builtin_amdgcn_mfma_f32_16x16x16f16(aF[k], bF[k], zero, 0, 0, 0);
      #pragma unroll
      for (int r = 0; r < 4; ++r) {
        const float d = __builtin_amdgcn_sqrtf(fmaxf(d2[r], EPSF));
        dacc[r] = fmaf(d, w16[k], dacc[r]);
      }
    }
  }

  // epilogue: out[q, b] = dacc + macc + bias[b]
  const float bv = bias[btile * 16 + l15];
  #pragma unroll
  for (int r = 0; r < 4; ++r) {
    const int q = qtile * 16 + lrow * 4 + r;
    out[(size_t)q * NBINS + btile * 16 + l15] = dacc[r] + macc[r] + bv;
  }
}

extern "C" void kernel_launch(void* const* d_in, const int* in_sizes, int n_in,
                              void* d_out, int out_size, void* d_ws, size_t ws_size,
                              hipStream_t stream) {
  const float* Q      = (const float*)d_in[0];
  const float* probes = (const float*)d_in[1];
  const float* wraw   = (const float*)d_in[2];
  const float* mw     = (const float*)d_in[3];
  const float* bias   = (const float*)d_in[4];
  float* out = (float*)d_out;
  unsigned* ws = (unsigned*)d_ws;  // needs ~11.2 MB; harness provides 256 MB

  prologue15<<<QN_BLOCKS + PB_BLOCKS, 256, 0, stream>>>(Q, probes, wraw, mw, ws);
  scorer15<<<2048, 256, 0, stream>>>(ws, bias, out);
}

// Round 16
// 37.679 us; speedup vs baseline: 1.8517x; 1.8416x over previous
//
#include <hip/hip_runtime.h>

#define NBINS 128
#define NFREQ 64
#define HDIM 128
#define NQ 16384
#define EPSF 1e-8f

typedef _Float16 h2 __attribute__((ext_vector_type(2)));
#define B2(x) __builtin_bit_cast(h2, (x))
#define U32(x) __builtin_bit_cast(unsigned, (x))

__device__ __forceinline__ h2 cvt_pk(float a, float b) {
  return __builtin_bit_cast(h2, __builtin_amdgcn_cvt_pkrtz(a, b));
}

// d_ws layout (f16 probe pack, 64 KiB; identical to rounds 9/11/12):
//   EP[c][b][fj] : (pr,pi) h2 word; c=0..7 (8-freq chunk), b=0..127, fj=0..7
//                  word idx (c*128+b)*8+fj                       -> 32 KiB
//   WP[c][b][fp] : (-softplus(w)) h2 pairs                       -> @ +8192 words
//   MP[c][b][fp] : (mw) h2 pairs                                 -> @ +12288 words
#define WS_NEEDED (64 * 1024)

// ---------- probe-pack kernel (unchanged) ----------
__global__ __launch_bounds__(256) void pack8(
    const float* __restrict__ probes,
    const float* __restrict__ wraw,
    const float* __restrict__ mw,
    unsigned* __restrict__ ws) {
  const int id = blockIdx.x * 256 + threadIdx.x;  // 1024 threads: (c,b)
  if (id >= 1024) return;
  const int c = id >> 7, b = id & 127;
  const float* pb = probes + b * HDIM + c * 8;
  const float* wb = wraw + b * NFREQ + c * 8;
  const float* mb = mw + b * NFREQ + c * 8;
  float pr[8], pi[8], w[8], m[8];
  *reinterpret_cast<float4*>(&pr[0]) = *reinterpret_cast<const float4*>(pb);
  *reinterpret_cast<float4*>(&pr[4]) = *reinterpret_cast<const float4*>(pb + 4);
  *reinterpret_cast<float4*>(&pi[0]) = *reinterpret_cast<const float4*>(pb + NFREQ);
  *reinterpret_cast<float4*>(&pi[4]) = *reinterpret_cast<const float4*>(pb + NFREQ + 4);
  *reinterpret_cast<float4*>(&w[0])  = *reinterpret_cast<const float4*>(wb);
  *reinterpret_cast<float4*>(&w[4])  = *reinterpret_cast<const float4*>(wb + 4);
  *reinterpret_cast<float4*>(&m[0])  = *reinterpret_cast<const float4*>(mb);
  *reinterpret_cast<float4*>(&m[4])  = *reinterpret_cast<const float4*>(mb + 4);
  unsigned ep[8], wp[4], mp[4];
  #pragma unroll
  for (int j = 0; j < 8; ++j) {
    h2 v = {(_Float16)pr[j], (_Float16)pi[j]};
    ep[j] = U32(v);
  }
  #pragma unroll
  for (int k = 0; k < 4; ++k) {
    float w0 = w[2 * k], w1 = w[2 * k + 1];
    float n0 = -(fmaxf(w0, 0.0f) + log1pf(expf(-fabsf(w0))));  // -softplus
    float n1 = -(fmaxf(w1, 0.0f) + log1pf(expf(-fabsf(w1))));
    h2 vw = {(_Float16)n0, (_Float16)n1};
    h2 vm = {(_Float16)m[2 * k], (_Float16)m[2 * k + 1]};
    wp[k] = U32(vw);
    mp[k] = U32(vm);
  }
  unsigned* EP = ws + (size_t)(c * 128 + b) * 8;
  *reinterpret_cast<uint4*>(EP)     = make_uint4(ep[0], ep[1], ep[2], ep[3]);
  *reinterpret_cast<uint4*>(EP + 4) = make_uint4(ep[4], ep[5], ep[6], ep[7]);
  unsigned* WP = ws + 8192 + (size_t)(c * 128 + b) * 4;
  *reinterpret_cast<uint4*>(WP) = make_uint4(wp[0], wp[1], wp[2], wp[3]);
  unsigned* MP = ws + 12288 + (size_t)(c * 128 + b) * 4;
  *reinterpret_cast<uint4*>(MP) = make_uint4(mp[0], mp[1], mp[2], mp[3]);
}

// ---------- scorer16: r12 math, fq-quartered for 2x wave oversubscription ----------
// Block = 256 thr = 4 waves = fq quarters 0..3 of the SAME 4 queries.
// Wave = 4q x 128 bins (lane=bin, 2 copies) x 16 freqs. 16384 waves total
// (2x chip residency) for finer scheduling granularity / tail balance.
__global__ __launch_bounds__(256) void scorer16(
    const float* __restrict__ Q,
    const unsigned* __restrict__ ws,
    const float* __restrict__ bias,
    float* __restrict__ out) {
  __shared__ __align__(16) unsigned qep[4 * 64];  // [q][f] (nqr,nqi) h2 ; 1 KB
  __shared__ __align__(16) unsigned qqm[4 * 32];  // [q][fp] (qm0,qm1) h2 ; 0.5 KB
  __shared__ float part[3][4][2][64];             // fq 1..3 partials ; 6 KB
  const int t = threadIdx.x;
  const int qblk = blockIdx.x * 4;

  // ---- Phase 1: normalize the block's 4 queries (32 lanes/query; t<128) ----
  if (t < 128) {
    const int q = t >> 5;          // 0..3
    const int seg = t & 31;        // freq pair: f = seg*2, seg*2+1
    const float* qp = Q + (size_t)(qblk + q) * HDIM + seg * 2;
    const float2 r = *reinterpret_cast<const float2*>(qp);
    const float2 i = *reinterpret_cast<const float2*>(qp + NFREQ);
    float s = r.x * r.x + r.y * r.y + i.x * i.x + i.y * i.y;
    s += __shfl_xor(s, 1, 32);
    s += __shfl_xor(s, 2, 32);
    s += __shfl_xor(s, 4, 32);
    s += __shfl_xor(s, 8, 32);
    s += __shfl_xor(s, 16, 32);
    const float inv = 1.0f / (__builtin_amdgcn_sqrtf(s) + EPSF);
    const float qr0 = r.x * inv, qi0 = i.x * inv;
    const float qr1 = r.y * inv, qi1 = i.y * inv;
    h2 e0 = {(_Float16)(-qr0), (_Float16)(-qi0)};
    h2 e1 = {(_Float16)(-qr1), (_Float16)(-qi1)};
    *reinterpret_cast<uint2*>(&qep[q * 64 + seg * 2]) = make_uint2(U32(e0), U32(e1));
    const float qm0 = __builtin_amdgcn_sqrtf(fmaf(qr0, qr0, fmaf(qi0, qi0, EPSF)));
    const float qm1 = __builtin_amdgcn_sqrtf(fmaf(qr1, qr1, fmaf(qi1, qi1, EPSF)));
    h2 vm = {(_Float16)qm0, (_Float16)qm1};
    qqm[q * 32 + seg] = U32(vm);
  }
  __syncthreads();

  // ---- Phase 2: main loop (this wave's 16-freq quarter) ----
  const int lane = t & 63;
  const int fq = __builtin_amdgcn_readfirstlane(t >> 6);

  float acc[4][2];
  #pragma unroll
  for (int q = 0; q < 4; ++q) acc[q][0] = acc[q][1] = 0.0f;

  #pragma unroll 1
  for (int ci = 0; ci < 2; ++ci) {
    const int c = fq * 2 + ci;
    // per-lane probe words for this 8-freq chunk, both bin-copies (32 u32)
    const unsigned* EPb = ws + (size_t)(c * 128 + lane) * 8;
    const unsigned* WPb = ws + 8192 + (size_t)(c * 128 + lane) * 4;
    const unsigned* MPb = ws + 12288 + (size_t)(c * 128 + lane) * 4;
    const uint4 e0a = *reinterpret_cast<const uint4*>(EPb);
    const uint4 e0b = *reinterpret_cast<const uint4*>(EPb + 4);
    const uint4 e1a = *reinterpret_cast<const uint4*>(EPb + 512);
    const uint4 e1b = *reinterpret_cast<const uint4*>(EPb + 516);
    const uint4 w0v = *reinterpret_cast<const uint4*>(WPb);
    const uint4 w1v = *reinterpret_cast<const uint4*>(WPb + 256);
    const uint4 m0v = *reinterpret_cast<const uint4*>(MPb);
    const uint4 m1v = *reinterpret_cast<const uint4*>(MPb + 256);
    const unsigned ep[2][8] = {
        {e0a.x, e0a.y, e0a.z, e0a.w, e0b.x, e0b.y, e0b.z, e0b.w},
        {e1a.x, e1a.y, e1a.z, e1a.w, e1b.x, e1b.y, e1b.z, e1b.w}};
    const unsigned wp[2][4] = {{w0v.x, w0v.y, w0v.z, w0v.w},
                               {w1v.x, w1v.y, w1v.z, w1v.w}};
    const unsigned mp[2][4] = {{m0v.x, m0v.y, m0v.z, m0v.w},
                               {m1v.x, m1v.y, m1v.z, m1v.w}};
    #pragma unroll
    for (int q = 0; q < 4; ++q) {
      #pragma unroll
      for (int half = 0; half < 2; ++half) {
        const uint4 qa = *reinterpret_cast<const uint4*>(&qep[q * 64 + c * 8 + half * 4]);
        const uint2 qm2 = *reinterpret_cast<const uint2*>(&qqm[q * 32 + c * 4 + half * 2]);
        const unsigned qe[4] = {qa.x, qa.y, qa.z, qa.w};
        const unsigned qmw[2] = {qm2.x, qm2.y};
        #pragma unroll
        for (int bc = 0; bc < 2; ++bc) {
          float da = acc[q][bc];
          #pragma unroll
          for (int fp = 0; fp < 2; ++fp) {
            const int wi = half * 4 + 2 * fp;
            h2 e0 = B2(ep[bc][wi])     + B2(qe[2 * fp]);      // v_pk_add_f16
            h2 e1 = B2(ep[bc][wi + 1]) + B2(qe[2 * fp + 1]);
            float d0 = __builtin_amdgcn_fdot2(e0, e0, EPSF, false);
            float d1 = __builtin_amdgcn_fdot2(e1, e1, EPSF, false);
            h2 dp = cvt_pk(__builtin_amdgcn_sqrtf(d0), __builtin_amdgcn_sqrtf(d1));
            da = __builtin_amdgcn_fdot2(dp, B2(wp[bc][half * 2 + fp]), da, false);
            da = __builtin_amdgcn_fdot2(B2(qmw[fp]), B2(mp[bc][half * 2 + fp]), da, false);
          }
          acc[q][bc] = da;
        }
      }
    }
  }

  // ---- Phase 3: 4-way fq-combine + store ----
  if (fq != 0) {
    #pragma unroll
    for (int q = 0; q < 4; ++q) {
      part[fq - 1][q][0][lane] = acc[q][0];
      part[fq - 1][q][1][lane] = acc[q][1];
    }
  }
  __syncthreads();
  if (fq == 0) {
    const float bias0 = bias[lane];
    const float bias1 = bias[64 + lane];
    #pragma unroll
    for (int q = 0; q < 4; ++q) {
      const size_t row = (size_t)(qblk + q) * NBINS;
      out[row + lane] = acc[q][0] + part[0][q][0][lane] + part[1][q][0][lane] +
                        part[2][q][0][lane] + bias0;
      out[row + 64 + lane] = acc[q][1] + part[0][q][1][lane] + part[1][q][1][lane] +
                             part[2][q][1][lane] + bias1;
    }
  }
}

extern "C" void kernel_launch(void* const* d_in, const int* in_sizes, int n_in,
                              void* d_out, int out_size, void* d_ws, size_t ws_size,
                              hipStream_t stream) {
  const float* Q      = (const float*)d_in[0];
  const float* probes = (const float*)d_in[1];
  const float* wraw   = (const float*)d_in[2];
  const float* mw     = (const float*)d_in[3];
  const float* bias   = (const float*)d_in[4];
  float* out = (float*)d_out;
  unsigned* ws = (unsigned*)d_ws;  // 64 KiB needed

  pack8<<<4, 256, 0, stream>>>(probes, wraw, mw, ws);
  scorer16<<<NQ / 4, 256, 0, stream>>>(Q, ws, bias, out);
}